// Round 1
// baseline (97.224 us; speedup 1.0000x reference)
//
#include <hip/hip_runtime.h>
#include <math.h>

#define L_SEQ  262144
#define NEIG   64
#define CHUNKS 2048
#define BLEN   128            // L_SEQ / CHUNKS
#define SPAN   (CHUNKS / 64)  // chunks per lane in the scan kernel = 32

// ---------------------------------------------------------------------------
// Phase 1: per-chunk local scan with zero initial state.
// Block = one chunk, 64 lanes = 64 eigenvalues. Writes carry S[c][n] (complex).
// ---------------------------------------------------------------------------
__global__ __launch_bounds__(64) void s4d_carry_kernel(
    const float* __restrict__ u,
    const float* __restrict__ A_re,
    const float* __restrict__ A_im,
    const float* __restrict__ log_step,
    float2* __restrict__ carries)
{
    __shared__ float u_lds[BLEN];
    const int c    = blockIdx.x;
    const int lane = threadIdx.x;

    // coalesced stage of this chunk's u into LDS (2 floats/lane)
    ((float2*)u_lds)[lane] = ((const float2*)(u + c * BLEN))[lane];
    __syncthreads();

    // per-eigenvalue constants in double (once per thread)
    const double dt = exp((double)log_step[0]);
    const double ar = (double)A_re[lane], ai = (double)A_im[lane];
    const double m  = exp(dt * ar);
    const float zr = (float)(m * cos(dt * ai));
    const float zi = (float)(m * sin(dt * ai));

    float xr = 0.f, xi = 0.f;
    #pragma unroll 8
    for (int t = 0; t < BLEN; ++t) {
        const float uv = u_lds[t];                 // broadcast read
        const float nr = fmaf(zr, xr, fmaf(-zi, xi, uv));
        const float ni = fmaf(zi, xr, zr * xi);
        xr = nr; xi = ni;
    }
    carries[c * NEIG + lane] = make_float2(xr, xi); // coalesced 8B/lane
}

// ---------------------------------------------------------------------------
// Phase 2: exclusive scan over chunk carries, per eigenvalue.
// Block = one eigenvalue n; lane l owns contiguous chunks [32l, 32l+32).
// In-place: carries[c][n] is replaced by the state BEFORE chunk c.
// ---------------------------------------------------------------------------
__global__ __launch_bounds__(64) void s4d_scan_kernel(
    const float* __restrict__ A_re,
    const float* __restrict__ A_im,
    const float* __restrict__ log_step,
    float2* __restrict__ carries)
{
    __shared__ float2 bspan[64];
    __shared__ float2 excl[64];
    const int n    = blockIdx.x;
    const int lane = threadIdx.x;

    const double dt = exp((double)log_step[0]);
    const double ar = (double)A_re[n], ai = (double)A_im[n];
    // zB = z^BLEN  (phase up to ~2.5e3 rad -> double range reduction)
    const double mB = exp(dt * ar * BLEN);
    const double aB = dt * ai * (double)BLEN;
    const float zBr = (float)(mB * cos(aB));
    const float zBi = (float)(mB * sin(aB));

    // phase i: lane-local reduce over its span (zero init)
    float br = 0.f, bi = 0.f;
    const int c0 = lane * SPAN;
    for (int k = 0; k < SPAN; ++k) {
        const float2 s = carries[(c0 + k) * NEIG + n];
        const float nr = fmaf(zBr, br, fmaf(-zBi, bi, s.x));
        const float ni = fmaf(zBi, br, fmaf(zBr, bi, s.y));
        br = nr; bi = ni;
    }
    bspan[lane] = make_float2(br, bi);
    __syncthreads();

    // phase ii: lane 0 does the 64-span exclusive scan, W = z^(BLEN*SPAN)
    if (lane == 0) {
        const double mW = exp(dt * ar * (double)BLEN * SPAN);
        const double aW = dt * ai * (double)BLEN * SPAN;   // up to ~8e4 rad, f64 ok
        const float Wr = (float)(mW * cos(aW));
        const float Wi = (float)(mW * sin(aW));
        float Xr = 0.f, Xi = 0.f;
        for (int l = 0; l < 64; ++l) {
            excl[l] = make_float2(Xr, Xi);
            const float2 b = bspan[l];
            const float nr = fmaf(Wr, Xr, fmaf(-Wi, Xi, b.x));
            const float ni = fmaf(Wi, Xr, fmaf(Wr, Xi, b.y));
            Xr = nr; Xi = ni;
        }
    }
    __syncthreads();

    // phase iii: re-emit exclusive per-chunk states (read S, overwrite in place)
    float2 X = excl[lane];
    float xr = X.x, xi = X.y;
    for (int k = 0; k < SPAN; ++k) {
        const int idx = (c0 + k) * NEIG + n;
        const float2 s = carries[idx];
        carries[idx] = make_float2(xr, xi);
        const float nr = fmaf(zBr, xr, fmaf(-zBi, xi, s.x));
        const float ni = fmaf(zBi, xr, fmaf(zBr, xi, s.y));
        xr = nr; xi = ni;
    }
}

// ---------------------------------------------------------------------------
// Phase 3: resume scan per chunk from exclusive state, reduce over eigenvalues,
// emit y. Block = one chunk, lane = eigenvalue. Butterfly __shfl_xor gives the
// 64-lane sum in every lane; lane (t mod 64) keeps y[t]; coalesced stores.
// ---------------------------------------------------------------------------
__global__ __launch_bounds__(64) void s4d_out_kernel(
    const float* __restrict__ u,
    const float* __restrict__ A_re,
    const float* __restrict__ A_im,
    const float* __restrict__ Cmat,
    const float* __restrict__ Dv,
    const float* __restrict__ log_step,
    const float2* __restrict__ prefix,
    float* __restrict__ y)
{
    __shared__ float u_lds[BLEN];
    const int c    = blockIdx.x;
    const int lane = threadIdx.x;

    ((float2*)u_lds)[lane] = ((const float2*)(u + c * BLEN))[lane];
    __syncthreads();

    const double dt = exp((double)log_step[0]);
    const double ar = (double)A_re[lane], ai = (double)A_im[lane];
    const double m  = exp(dt * ar);
    const double zr_d = m * cos(dt * ai);
    const double zi_d = m * sin(dt * ai);
    // coeff = Ct * (exp(dtA) - 1) / A   (complex, in double)
    const double er = zr_d - 1.0, ei = zi_d;
    const double den = ar * ar + ai * ai;
    const double qr = (er * ar + ei * ai) / den;
    const double qi = (ei * ar - er * ai) / den;
    const double cr = (double)Cmat[2 * lane], ci = (double)Cmat[2 * lane + 1];
    const float gr = (float)(cr * qr - ci * qi);
    const float gi = (float)(cr * qi + ci * qr);
    const float zr = (float)zr_d, zi = (float)zi_d;
    const float Dval = Dv[0];

    const float2 X = prefix[c * NEIG + lane];
    float xr = X.x, xi = X.y;
    float* yc = y + c * BLEN;

    #pragma unroll
    for (int q = 0; q < BLEN / 64; ++q) {
        float yk = 0.f;
        for (int j = 0; j < 64; ++j) {
            const float uv = u_lds[q * 64 + j];
            const float nr = fmaf(zr, xr, fmaf(-zi, xi, uv));
            const float ni = fmaf(zi, xr, zr * xi);
            xr = nr; xi = ni;
            float r = fmaf(gr, xr, -gi * xi);
            r += __shfl_xor(r, 1, 64);
            r += __shfl_xor(r, 2, 64);
            r += __shfl_xor(r, 4, 64);
            r += __shfl_xor(r, 8, 64);
            r += __shfl_xor(r, 16, 64);
            r += __shfl_xor(r, 32, 64);
            if (lane == j) yk = fmaf(Dval, uv, r);
        }
        yc[q * 64 + lane] = yk;   // coalesced
    }
}

// ---------------------------------------------------------------------------
extern "C" void kernel_launch(void* const* d_in, const int* in_sizes, int n_in,
                              void* d_out, int out_size, void* d_ws, size_t ws_size,
                              hipStream_t stream)
{
    const float* u    = (const float*)d_in[0];
    const float* A_re = (const float*)d_in[1];
    const float* A_im = (const float*)d_in[2];
    const float* Cmat = (const float*)d_in[3];
    const float* Dv   = (const float*)d_in[4];
    const float* ls   = (const float*)d_in[5];
    float* y = (float*)d_out;
    float2* carr = (float2*)d_ws;   // CHUNKS*NEIG*8 = 1 MB

    hipLaunchKernelGGL(s4d_carry_kernel, dim3(CHUNKS), dim3(64), 0, stream,
                       u, A_re, A_im, ls, carr);
    hipLaunchKernelGGL(s4d_scan_kernel, dim3(NEIG), dim3(64), 0, stream,
                       A_re, A_im, ls, carr);
    hipLaunchKernelGGL(s4d_out_kernel, dim3(CHUNKS), dim3(64), 0, stream,
                       u, A_re, A_im, Cmat, Dv, ls, carr, y);
}

// Round 2
// 82.037 us; speedup vs baseline: 1.1851x; 1.1851x over previous
//
#include <hip/hip_runtime.h>
#include <math.h>

#define L_SEQ  262144
#define NEIG   64
#define CHUNKS 2048
#define BLEN   128            // L_SEQ / CHUNKS
#define SPAN   (CHUNKS / 64)  // chunks per lane in the scan kernel = 32

// exp(mag_arg) * (cos(ang), sin(ang)); f64 used ONLY for mults/trunc in the
// angle range reduction (ang up to ~8e4 rad), transcendentals are fp32 HW ops.
__device__ __forceinline__ float2 cexpf_rr(double mag_arg, double ang)
{
    const double TWO_PI  = 6.283185307179586476;
    const double INV_2PI = 0.15915494309189533577;
    double q    = ang * INV_2PI;
    double frac = q - trunc(q);
    float  af   = (float)(frac * TWO_PI);
    float s, c;
    __sincosf(af, &s, &c);
    float m = __expf((float)mag_arg);
    return make_float2(m * c, m * s);
}

// ---------------------------------------------------------------------------
// Phase 1: per-chunk local scan, zero init. Block = chunk, lane = eigenvalue.
// ---------------------------------------------------------------------------
__global__ __launch_bounds__(64) void s4d_carry_kernel(
    const float* __restrict__ u,
    const float* __restrict__ A_re,
    const float* __restrict__ A_im,
    const float* __restrict__ log_step,
    float2* __restrict__ carries)
{
    __shared__ float u_lds[BLEN];
    const int c    = blockIdx.x;
    const int lane = threadIdx.x;

    ((float2*)u_lds)[lane] = ((const float2*)(u + c * BLEN))[lane];

    const double dt = (double)__expf(log_step[0]);
    const double ar = (double)A_re[lane], ai = (double)A_im[lane];
    const float2 z  = cexpf_rr(dt * ar, dt * ai);
    const float zr = z.x, zi = z.y;
    __syncthreads();

    float xr = 0.f, xi = 0.f;
    #pragma unroll
    for (int t4 = 0; t4 < BLEN / 4; ++t4) {
        const float4 uv4 = ((const float4*)u_lds)[t4];   // broadcast b128
        #pragma unroll
        for (int j = 0; j < 4; ++j) {
            const float uv = (j == 0) ? uv4.x : (j == 1) ? uv4.y
                           : (j == 2) ? uv4.z : uv4.w;
            const float nr = fmaf(zr, xr, fmaf(-zi, xi, uv));
            const float ni = fmaf(zi, xr, zr * xi);
            xr = nr; xi = ni;
        }
    }
    carries[c * NEIG + lane] = make_float2(xr, xi);      // coalesced
}

// ---------------------------------------------------------------------------
// Phase 2: exclusive scan over chunk carries, per eigenvalue. Block = eigen n.
// ---------------------------------------------------------------------------
__global__ __launch_bounds__(64) void s4d_scan_kernel(
    const float* __restrict__ A_re,
    const float* __restrict__ A_im,
    const float* __restrict__ log_step,
    float2* __restrict__ carries)
{
    __shared__ float2 bspan[64];
    __shared__ float2 excl[64];
    const int n    = blockIdx.x;
    const int lane = threadIdx.x;

    const double dt = (double)__expf(log_step[0]);
    const double ar = (double)A_re[n], ai = (double)A_im[n];
    const float2 zB = cexpf_rr(dt * ar * (double)BLEN, dt * ai * (double)BLEN);
    const float zBr = zB.x, zBi = zB.y;

    // i: lane-local reduce over its span (zero init)
    float br = 0.f, bi = 0.f;
    const int c0 = lane * SPAN;
    #pragma unroll 4
    for (int k = 0; k < SPAN; ++k) {
        const float2 s = carries[(c0 + k) * NEIG + n];
        const float nr = fmaf(zBr, br, fmaf(-zBi, bi, s.x));
        const float ni = fmaf(zBi, br, fmaf(zBr, bi, s.y));
        br = nr; bi = ni;
    }
    bspan[lane] = make_float2(br, bi);
    __syncthreads();

    // ii: lane 0 exclusive-scans the 64 span results with W = z^(BLEN*SPAN)
    if (lane == 0) {
        const float2 W = cexpf_rr(dt * ar * (double)(BLEN * SPAN),
                                  dt * ai * (double)(BLEN * SPAN));
        float Xr = 0.f, Xi = 0.f;
        for (int l = 0; l < 64; ++l) {
            excl[l] = make_float2(Xr, Xi);
            const float2 b = bspan[l];
            const float nr = fmaf(W.x, Xr, fmaf(-W.y, Xi, b.x));
            const float ni = fmaf(W.y, Xr, fmaf(W.x, Xi, b.y));
            Xr = nr; Xi = ni;
        }
    }
    __syncthreads();

    // iii: re-emit exclusive per-chunk states in place
    float2 X = excl[lane];
    float xr = X.x, xi = X.y;
    #pragma unroll 4
    for (int k = 0; k < SPAN; ++k) {
        const int idx = (c0 + k) * NEIG + n;
        const float2 s = carries[idx];
        carries[idx] = make_float2(xr, xi);
        const float nr = fmaf(zBr, xr, fmaf(-zBi, xi, s.x));
        const float ni = fmaf(zBi, xr, fmaf(zBr, xi, s.y));
        xr = nr; xi = ni;
    }
}

// ---------------------------------------------------------------------------
// Phase 3: resume from exclusive state; contributions go to an LDS matrix
// contrib[t][n] (stride 65 -> conflict-free); one parallel reduction per
// 32-step subtile replaces the per-step 6-shuffle butterfly.
// ---------------------------------------------------------------------------
__global__ __launch_bounds__(64) void s4d_out_kernel(
    const float* __restrict__ u,
    const float* __restrict__ A_re,
    const float* __restrict__ A_im,
    const float* __restrict__ Cmat,
    const float* __restrict__ Dv,
    const float* __restrict__ log_step,
    const float2* __restrict__ prefix,
    float* __restrict__ y)
{
    __shared__ float u_lds[BLEN];
    __shared__ float contrib[32 * 65];
    const int c    = blockIdx.x;
    const int lane = threadIdx.x;

    ((float2*)u_lds)[lane] = ((const float2*)(u + c * BLEN))[lane];

    const double dt = (double)__expf(log_step[0]);
    const double ar = (double)A_re[lane], ai = (double)A_im[lane];
    const float2 z  = cexpf_rr(dt * ar, dt * ai);
    const float zr = z.x, zi = z.y;

    // g = Ct * (z - 1) / A
    const float arf = (float)ar, aif = (float)ai;
    const float er = z.x - 1.f, ei = z.y;
    const float den = arf * arf + aif * aif;
    const float qr = (er * arf + ei * aif) / den;
    const float qi = (ei * arf - er * aif) / den;
    const float cr = Cmat[2 * lane], ci = Cmat[2 * lane + 1];
    const float gr = fmaf(cr, qr, -ci * qi);
    const float gi = fmaf(cr, qi,  ci * qr);
    const float Dval = Dv[0];

    const float2 X = prefix[c * NEIG + lane];
    float xr = X.x, xi = X.y;
    float* yc = y + c * BLEN;
    const int  t_red = lane & 31;
    const int  hoff  = (lane >> 5) << 5;    // 0 or 32
    __syncthreads();

    #pragma unroll
    for (int sub = 0; sub < BLEN / 32; ++sub) {
        #pragma unroll
        for (int t4 = 0; t4 < 8; ++t4) {
            const float4 uv4 = ((const float4*)u_lds)[sub * 8 + t4];
            #pragma unroll
            for (int j = 0; j < 4; ++j) {
                const float uv = (j == 0) ? uv4.x : (j == 1) ? uv4.y
                               : (j == 2) ? uv4.z : uv4.w;
                const float nr = fmaf(zr, xr, fmaf(-zi, xi, uv));
                const float ni = fmaf(zi, xr, zr * xi);
                xr = nr; xi = ni;
                contrib[(t4 * 4 + j) * 65 + lane] = fmaf(gr, xr, -gi * xi);
            }
        }
        __syncthreads();
        float r = 0.f;
        #pragma unroll
        for (int k = 0; k < 32; ++k)
            r += contrib[t_red * 65 + hoff + k];
        r += __shfl_xor(r, 32, 64);
        if (lane < 32) {
            const float uv = u_lds[sub * 32 + lane];
            yc[sub * 32 + lane] = fmaf(Dval, uv, r);   // coalesced 128B
        }
        __syncthreads();
    }
}

// ---------------------------------------------------------------------------
extern "C" void kernel_launch(void* const* d_in, const int* in_sizes, int n_in,
                              void* d_out, int out_size, void* d_ws, size_t ws_size,
                              hipStream_t stream)
{
    const float* u    = (const float*)d_in[0];
    const float* A_re = (const float*)d_in[1];
    const float* A_im = (const float*)d_in[2];
    const float* Cmat = (const float*)d_in[3];
    const float* Dv   = (const float*)d_in[4];
    const float* ls   = (const float*)d_in[5];
    float* y = (float*)d_out;
    float2* carr = (float2*)d_ws;   // CHUNKS*NEIG*8 = 1 MB

    hipLaunchKernelGGL(s4d_carry_kernel, dim3(CHUNKS), dim3(64), 0, stream,
                       u, A_re, A_im, ls, carr);
    hipLaunchKernelGGL(s4d_scan_kernel, dim3(NEIG), dim3(64), 0, stream,
                       A_re, A_im, ls, carr);
    hipLaunchKernelGGL(s4d_out_kernel, dim3(CHUNKS), dim3(64), 0, stream,
                       u, A_re, A_im, Cmat, Dv, ls, carr, y);
}